// Round 1
// baseline (811.190 us; speedup 1.0000x reference)
//
#include <hip/hip_runtime.h>
#include <cstddef>

#define C_CH 192
#define PK   9408      // C_CH * 49
#define D1   768
#define NROI 1000

// ---------------------------------------------------------------------------
// RoIAlign: one thread per output element pooled[n][c][i][j] (flat [n][PK])
// ---------------------------------------------------------------------------
__global__ __launch_bounds__(256) void roi_align_kernel(
    const float* __restrict__ f0, const float* __restrict__ f1,
    const float* __restrict__ f2, const float* __restrict__ f3,
    const float* __restrict__ rois, float* __restrict__ pooled, int n_rois)
{
    int idx = blockIdx.x * 256 + threadIdx.x;
    int total = n_rois * PK;
    if (idx >= total) return;
    int n  = idx / PK;
    int r  = idx - n * PK;
    int c  = r / 49;
    int ij = r - c * 49;
    int i  = ij / 7;
    int j  = ij - i * 7;

    float by1 = rois[n*5+0], bx1 = rois[n*5+1];
    float by2 = rois[n*5+2], bx2 = rois[n*5+3];
    int   b   = (int)rois[n*5+4];

    float hh = by2 - by1, ww = bx2 - bx1;
    int lvl = (int)rintf(4.0f + log2f(sqrtf(hh * ww)));   // round-half-even, matches jnp.round
    lvl = min(max(lvl, 0), 3);

    const float* fmap; int H;
    if      (lvl == 0) { fmap = f0; H = 128; }
    else if (lvl == 1) { fmap = f1; H = 64;  }
    else if (lvl == 2) { fmap = f2; H = 32;  }
    else               { fmap = f3; H = 16;  }
    float Hf = (float)H;

    float y1p = by1 * Hf, x1p = bx1 * Hf;
    float y2p = by2 * Hf, x2p = bx2 * Hf;
    float bin_h = fmaxf(y2p - y1p, 1.0f) * (1.0f / 7.0f);
    float bin_w = fmaxf(x2p - x1p, 1.0f) * (1.0f / 7.0f);

    int HW = H * H;
    const float* base = fmap + ((size_t)b * C_CH + c) * (size_t)HW;

    float acc = 0.0f;
    #pragma unroll
    for (int sy = 0; sy < 2; ++sy) {
        float gy = (float)i + 0.25f + 0.5f * (float)sy;
        float y  = y1p + gy * bin_h;
        bool  vy = (y >= -1.0f) && (y <= Hf);
        float yc = fminf(fmaxf(y, 0.0f), Hf - 1.0f);
        int   y0 = (int)floorf(yc);
        float ly = yc - (float)y0;
        int   y1i = min(y0 + 1, H - 1);
        #pragma unroll
        for (int sx = 0; sx < 2; ++sx) {
            float gx = (float)j + 0.25f + 0.5f * (float)sx;
            float x  = x1p + gx * bin_w;
            bool  vx = (x >= -1.0f) && (x <= Hf);
            float xc = fminf(fmaxf(x, 0.0f), Hf - 1.0f);
            int   x0 = (int)floorf(xc);
            float lx = xc - (float)x0;
            int   x1i = min(x0 + 1, H - 1);
            if (vy && vx) {
                float v00 = base[y0 * H + x0];
                float v01 = base[y0 * H + x1i];
                float v10 = base[y1i * H + x0];
                float v11 = base[y1i * H + x1i];
                float v = v00 * (1.0f - ly) * (1.0f - lx)
                        + v01 * (1.0f - ly) * lx
                        + v10 * ly * (1.0f - lx)
                        + v11 * ly * lx;
                acc += v;
            }
        }
    }
    pooled[idx] = acc * 0.25f;
}

// ---------------------------------------------------------------------------
// fp32 tiled GEMM: O[m][n] = relu(sum_k A[m][k] * W[n][k] + bias[n])
// BM=BN=64, BK=16, 256 threads, 4x4 microtile. N % 64 == 0, K % 16 == 0.
// ---------------------------------------------------------------------------
#define BM 64
#define BN 64
#define BK 16

__global__ __launch_bounds__(256) void fc_gemm_relu(
    const float* __restrict__ A, const float* __restrict__ W,
    const float* __restrict__ bias, float* __restrict__ O,
    int M, int N, int K)
{
    __shared__ float As[BK][BM + 4];
    __shared__ float Bs[BK][BN + 4];

    int tid = threadIdx.x;
    int m0 = blockIdx.y * BM;
    int n0 = blockIdx.x * BN;

    int lrow = tid >> 2;          // 0..63
    int lk4  = (tid & 3) * 4;     // 0,4,8,12

    int tm = (tid >> 4) * 4;      // 0..60
    int tn = (tid & 15) * 4;      // 0..60

    float acc[4][4] = {};

    for (int k0 = 0; k0 < K; k0 += BK) {
        // A tile (guard M)
        float4 av = make_float4(0.f, 0.f, 0.f, 0.f);
        int am = m0 + lrow;
        if (am < M) av = *(const float4*)(A + (size_t)am * K + k0 + lk4);
        As[lk4 + 0][lrow] = av.x;
        As[lk4 + 1][lrow] = av.y;
        As[lk4 + 2][lrow] = av.z;
        As[lk4 + 3][lrow] = av.w;
        // B tile (N multiple of 64 -> no guard)
        float4 bv = *(const float4*)(W + (size_t)(n0 + lrow) * K + k0 + lk4);
        Bs[lk4 + 0][lrow] = bv.x;
        Bs[lk4 + 1][lrow] = bv.y;
        Bs[lk4 + 2][lrow] = bv.z;
        Bs[lk4 + 3][lrow] = bv.w;
        __syncthreads();

        #pragma unroll
        for (int kk = 0; kk < BK; ++kk) {
            float4 a = *(const float4*)&As[kk][tm];
            float4 b = *(const float4*)&Bs[kk][tn];
            float ar[4] = {a.x, a.y, a.z, a.w};
            float br[4] = {b.x, b.y, b.z, b.w};
            #pragma unroll
            for (int ii = 0; ii < 4; ++ii)
                #pragma unroll
                for (int jj = 0; jj < 4; ++jj)
                    acc[ii][jj] = fmaf(ar[ii], br[jj], acc[ii][jj]);
        }
        __syncthreads();
    }

    #pragma unroll
    for (int ii = 0; ii < 4; ++ii) {
        int m = m0 + tm + ii;
        if (m >= M) continue;
        #pragma unroll
        for (int jj = 0; jj < 4; ++jj) {
            int n = n0 + tn + jj;
            float v = acc[ii][jj] + bias[n];
            O[(size_t)m * N + n] = fmaxf(v, 0.0f);
        }
    }
}

// ---------------------------------------------------------------------------
// Heads: 14 outputs per RoI, K=768 dot each, scattered into d_out layout:
//   [bbox (n,2,4)=8000][cls (n,2)=2000][regress (n,2,2)=4000 (reg,unc)]
// ---------------------------------------------------------------------------
__global__ __launch_bounds__(256) void heads_kernel(
    const float* __restrict__ Z,
    const float* __restrict__ w_bbox, const float* __restrict__ b_bbox,
    const float* __restrict__ w_cls,  const float* __restrict__ b_cls,
    const float* __restrict__ w_reg,  const float* __restrict__ b_reg,
    const float* __restrict__ w_unc,  const float* __restrict__ b_unc,
    float* __restrict__ out, int n_rois)
{
    int idx = blockIdx.x * 256 + threadIdx.x;
    if (idx >= n_rois * 14) return;
    int n = idx / 14;
    int o = idx - n * 14;

    const float* w; float bb;
    if      (o < 8)  { w = w_bbox + o * D1;        bb = b_bbox[o]; }
    else if (o < 10) { w = w_cls  + (o - 8) * D1;  bb = b_cls[o - 8]; }
    else if (o < 12) { w = w_reg  + (o - 10) * D1; bb = b_reg[o - 10]; }
    else             { w = w_unc  + (o - 12) * D1; bb = b_unc[o - 12]; }

    const float* z = Z + (size_t)n * D1;
    float s = bb;
    for (int k = 0; k < D1; k += 4) {
        float4 zv = *(const float4*)(z + k);
        float4 wv = *(const float4*)(w + k);
        s = fmaf(zv.x, wv.x, s);
        s = fmaf(zv.y, wv.y, s);
        s = fmaf(zv.z, wv.z, s);
        s = fmaf(zv.w, wv.w, s);
    }

    int off;
    int clsOff = n_rois * 8;
    int regOff = n_rois * 8 + n_rois * 2;
    if      (o < 8)  off = n * 8 + o;
    else if (o < 10) off = clsOff + n * 2 + (o - 8);
    else if (o < 12) off = regOff + n * 4 + (o - 10) * 2;       // reg -> slot 0
    else             off = regOff + n * 4 + (o - 12) * 2 + 1;   // unc -> slot 1
    out[off] = s;
}

// ---------------------------------------------------------------------------
extern "C" void kernel_launch(void* const* d_in, const int* in_sizes, int n_in,
                              void* d_out, int out_size, void* d_ws, size_t ws_size,
                              hipStream_t stream)
{
    const float* f0   = (const float*)d_in[0];
    const float* f1   = (const float*)d_in[1];
    const float* f2   = (const float*)d_in[2];
    const float* f3   = (const float*)d_in[3];
    const float* rois = (const float*)d_in[4];
    const float* w1   = (const float*)d_in[5];
    const float* b1   = (const float*)d_in[6];
    const float* w2   = (const float*)d_in[7];
    const float* b2   = (const float*)d_in[8];
    const float* w_bbox = (const float*)d_in[9];
    const float* b_bbox = (const float*)d_in[10];
    const float* w_cls  = (const float*)d_in[11];
    const float* b_cls  = (const float*)d_in[12];
    const float* w_reg  = (const float*)d_in[13];
    const float* b_reg  = (const float*)d_in[14];
    const float* w_unc  = (const float*)d_in[15];
    const float* b_unc  = (const float*)d_in[16];
    float* out = (float*)d_out;

    int n_rois = in_sizes[4] / 5;   // 1000

    // workspace layout (fp32): pooled [n_rois][PK], Y [n_rois][D1], Z [n_rois][D1]
    float* pooled = (float*)d_ws;
    float* Y = pooled + (size_t)n_rois * PK;
    float* Z = Y + (size_t)n_rois * D1;

    // 1) RoIAlign
    {
        int total = n_rois * PK;
        int blocks = (total + 255) / 256;
        roi_align_kernel<<<blocks, 256, 0, stream>>>(f0, f1, f2, f3, rois, pooled, n_rois);
    }
    // 2) FC1: [n_rois, PK] x [D1, PK]^T -> Y
    {
        dim3 grid(D1 / BN, (n_rois + BM - 1) / BM);
        fc_gemm_relu<<<grid, 256, 0, stream>>>(pooled, w1, b1, Y, n_rois, D1, PK);
    }
    // 3) FC2: [n_rois, D1] x [D1, D1]^T -> Z
    {
        dim3 grid(D1 / BN, (n_rois + BM - 1) / BM);
        fc_gemm_relu<<<grid, 256, 0, stream>>>(Y, w2, b2, Z, n_rois, D1, D1);
    }
    // 4) heads
    {
        int total = n_rois * 14;
        int blocks = (total + 255) / 256;
        heads_kernel<<<blocks, 256, 0, stream>>>(Z, w_bbox, b_bbox, w_cls, b_cls,
                                                 w_reg, b_reg, w_unc, b_unc, out, n_rois);
    }
}

// Round 2
// 346.903 us; speedup vs baseline: 2.3384x; 2.3384x over previous
//
#include <hip/hip_runtime.h>
#include <hip/hip_bf16.h>
#include <cstddef>

typedef __attribute__((ext_vector_type(8))) short short8;
typedef __attribute__((ext_vector_type(16))) float float16;

#define C_CH 192
#define PK   9408      // C_CH * 49
#define D1   768

// ---------------------------------------------------------------------------
// fp32 -> bf16 conversion (vectorized float4 -> 4x bf16)
// ---------------------------------------------------------------------------
__global__ __launch_bounds__(256) void cvt_bf16(const float* __restrict__ in,
                                                ushort* __restrict__ out, int n4)
{
    int i = blockIdx.x * 256 + threadIdx.x;
    if (i >= n4) return;
    float4 v = ((const float4*)in)[i];
    ushort4 o;
    o.x = __builtin_bit_cast(unsigned short, __float2bfloat16(v.x));
    o.y = __builtin_bit_cast(unsigned short, __float2bfloat16(v.y));
    o.z = __builtin_bit_cast(unsigned short, __float2bfloat16(v.z));
    o.w = __builtin_bit_cast(unsigned short, __float2bfloat16(v.w));
    ((ushort4*)out)[i] = o;
}

// ---------------------------------------------------------------------------
// RoIAlign: one thread per output element pooled[n][c][i][j] (flat [n][PK]), bf16 out
// ---------------------------------------------------------------------------
__global__ __launch_bounds__(256) void roi_align_kernel(
    const float* __restrict__ f0, const float* __restrict__ f1,
    const float* __restrict__ f2, const float* __restrict__ f3,
    const float* __restrict__ rois, ushort* __restrict__ pooled, int n_rois)
{
    int idx = blockIdx.x * 256 + threadIdx.x;
    int total = n_rois * PK;
    if (idx >= total) return;
    int n  = idx / PK;
    int r  = idx - n * PK;
    int c  = r / 49;
    int ij = r - c * 49;
    int i  = ij / 7;
    int j  = ij - i * 7;

    float by1 = rois[n*5+0], bx1 = rois[n*5+1];
    float by2 = rois[n*5+2], bx2 = rois[n*5+3];
    int   b   = (int)rois[n*5+4];

    float hh = by2 - by1, ww = bx2 - bx1;
    int lvl = (int)rintf(4.0f + log2f(sqrtf(hh * ww)));   // round-half-even, matches jnp.round
    lvl = min(max(lvl, 0), 3);

    const float* fmap; int H;
    if      (lvl == 0) { fmap = f0; H = 128; }
    else if (lvl == 1) { fmap = f1; H = 64;  }
    else if (lvl == 2) { fmap = f2; H = 32;  }
    else               { fmap = f3; H = 16;  }
    float Hf = (float)H;

    float y1p = by1 * Hf, x1p = bx1 * Hf;
    float y2p = by2 * Hf, x2p = bx2 * Hf;
    float bin_h = fmaxf(y2p - y1p, 1.0f) * (1.0f / 7.0f);
    float bin_w = fmaxf(x2p - x1p, 1.0f) * (1.0f / 7.0f);

    int HW = H * H;
    const float* base = fmap + ((size_t)b * C_CH + c) * (size_t)HW;

    float acc = 0.0f;
    #pragma unroll
    for (int sy = 0; sy < 2; ++sy) {
        float gy = (float)i + 0.25f + 0.5f * (float)sy;
        float y  = y1p + gy * bin_h;
        bool  vy = (y >= -1.0f) && (y <= Hf);
        float yc = fminf(fmaxf(y, 0.0f), Hf - 1.0f);
        int   y0 = (int)floorf(yc);
        float ly = yc - (float)y0;
        int   y1i = min(y0 + 1, H - 1);
        #pragma unroll
        for (int sx = 0; sx < 2; ++sx) {
            float gx = (float)j + 0.25f + 0.5f * (float)sx;
            float x  = x1p + gx * bin_w;
            bool  vx = (x >= -1.0f) && (x <= Hf);
            float xc = fminf(fmaxf(x, 0.0f), Hf - 1.0f);
            int   x0 = (int)floorf(xc);
            float lx = xc - (float)x0;
            int   x1i = min(x0 + 1, H - 1);
            if (vy && vx) {
                float v00 = base[y0 * H + x0];
                float v01 = base[y0 * H + x1i];
                float v10 = base[y1i * H + x0];
                float v11 = base[y1i * H + x1i];
                float v = v00 * (1.0f - ly) * (1.0f - lx)
                        + v01 * (1.0f - ly) * lx
                        + v10 * ly * (1.0f - lx)
                        + v11 * ly * lx;
                acc += v;
            }
        }
    }
    pooled[idx] = __builtin_bit_cast(unsigned short, __float2bfloat16(acc * 0.25f));
}

// ---------------------------------------------------------------------------
// bf16 MFMA GEMM: O[m][n] = relu(sum_k A[m][k]*W[n][k] + bias[n])
// 64x64 block tile, BK=64, 4 waves (each 32x32 via v_mfma_f32_32x32x16_bf16),
// depth-2 register prefetch + double-buffered LDS (1 barrier/iter).
// LDS layout per 16-k subtile ks, rowgroup g: 1KB block, position
// p = (h*32 + row) ^ (ks<<2) holds row's k-half h -> fragment read is lane^swz,
// conflict-free both directions. Global staging: 32B contiguous per lane.
// Requires N % 64 == 0, K % 64 == 0.
// ---------------------------------------------------------------------------
template<int OUT_BF16>
__global__ __launch_bounds__(256) void mfma_gemm_relu(
    const ushort* __restrict__ A,   // [M][K] bf16
    const ushort* __restrict__ W,   // [N][K] bf16
    const float*  __restrict__ bias,
    void* __restrict__ outp,
    int M, int N, int K)
{
    __shared__ char ldsA[2][8192];
    __shared__ char ldsB[2][8192];

    const int t    = threadIdx.x;
    const int lane = t & 63;
    const int wave = t >> 6;
    const int wm = wave >> 1, wn = wave & 1;

    const int m0 = blockIdx.y * 64;
    const int n0 = blockIdx.x * 64;

    // staging constants: thread t loads 32B (one 16-k subtile) of one row, per matrix
    const int ks   = t & 3;           // k-subtile (16 bf16)
    const int mrow = t >> 2;          // row within 64-tile
    const int g    = mrow >> 5;       // rowgroup
    const int rw   = mrow & 31;
    const int lof0 = ks*2048 + g*1024 + ((     rw) ^ (ks<<2))*16;   // h=0
    const int lof1 = ks*2048 + g*1024 + ((32 + rw) ^ (ks<<2))*16;   // h=1

    const int arow = min(m0 + mrow, M-1);
    const int brow = n0 + mrow;
    const ushort* ap = A + (size_t)arow * K + ks*16;
    const ushort* bp = W + (size_t)brow * K + ks*16;

    const int nk = K >> 6;

    float4 ra0, ra1, rb0, rb1;   // data for tile kt+1
    float4 qa0, qa1, qb0, qb1;   // data for tile kt+2 (in flight)

    // preload tile 0, stage into buf0
    ra0 = ((const float4*)ap)[0]; ra1 = ((const float4*)ap)[1];
    rb0 = ((const float4*)bp)[0]; rb1 = ((const float4*)bp)[1];
    *(float4*)&ldsA[0][lof0] = ra0; *(float4*)&ldsA[0][lof1] = ra1;
    *(float4*)&ldsB[0][lof0] = rb0; *(float4*)&ldsB[0][lof1] = rb1;
    // preload tile 1 into regs
    {
        int k1 = min(1, nk - 1);
        const ushort* ap1 = ap + (size_t)k1 * 64;
        const ushort* bp1 = bp + (size_t)k1 * 64;
        ra0 = ((const float4*)ap1)[0]; ra1 = ((const float4*)ap1)[1];
        rb0 = ((const float4*)bp1)[0]; rb1 = ((const float4*)bp1)[1];
    }
    __syncthreads();

    float16 acc = {};

    for (int kt = 0; kt < nk; ++kt) {
        // issue loads for tile kt+2 (clamped; redundant at tail, harmless)
        {
            int k2 = min(kt + 2, nk - 1);
            const ushort* ap2 = ap + (size_t)k2 * 64;
            const ushort* bp2 = bp + (size_t)k2 * 64;
            qa0 = ((const float4*)ap2)[0]; qa1 = ((const float4*)ap2)[1];
            qb0 = ((const float4*)bp2)[0]; qb1 = ((const float4*)bp2)[1];
        }

        // stage tile kt+1 into the other buffer (its last readers synced last iter)
        if (kt + 1 < nk) {
            char* dA = ldsA[(kt+1)&1]; char* dB = ldsB[(kt+1)&1];
            *(float4*)&dA[lof0] = ra0; *(float4*)&dA[lof1] = ra1;
            *(float4*)&dB[lof0] = rb0; *(float4*)&dB[lof1] = rb1;
        }

        // compute tile kt
        const char* sA = ldsA[kt&1]; const char* sB = ldsB[kt&1];
        #pragma unroll
        for (int s = 0; s < 4; ++s) {
            int ro = s*2048 + (lane ^ (s<<2))*16;
            short8 af = *(const short8*)&sA[wm*1024 + ro];
            short8 bf = *(const short8*)&sB[wn*1024 + ro];
            acc = __builtin_amdgcn_mfma_f32_32x32x16_bf16(af, bf, acc, 0, 0, 0);
        }

        __syncthreads();

        ra0 = qa0; ra1 = qa1; rb0 = qb0; rb1 = qb1;
    }

    // epilogue: C/D map (32x32): col=lane&31, row=(reg&3)+8*(reg>>2)+4*(lane>>5)
    const int col   = lane & 31;
    const int rbase = 4 * (lane >> 5);
    const int nG    = n0 + wn*32 + col;
    const float bv  = bias[nG];

    if (OUT_BF16) {
        ushort* O = (ushort*)outp;
        #pragma unroll
        for (int r = 0; r < 16; ++r) {
            int row = (r & 3) + 8*(r >> 2) + rbase;
            int mG  = m0 + wm*32 + row;
            if (mG < M) {
                float v = fmaxf(acc[r] + bv, 0.0f);
                O[(size_t)mG * N + nG] = __builtin_bit_cast(unsigned short, __float2bfloat16(v));
            }
        }
    } else {
        float* O = (float*)outp;
        #pragma unroll
        for (int r = 0; r < 16; ++r) {
            int row = (r & 3) + 8*(r >> 2) + rbase;
            int mG  = m0 + wm*32 + row;
            if (mG < M) {
                O[(size_t)mG * N + nG] = fmaxf(acc[r] + bv, 0.0f);
            }
        }
    }
}

// ---------------------------------------------------------------------------
// Heads: 14 outputs per RoI, K=768 fp32 dot each, scattered into d_out layout:
//   [bbox (n,2,4)=8000][cls (n,2)=2000][regress (n,2,2)=4000 (reg,unc)]
// ---------------------------------------------------------------------------
__global__ __launch_bounds__(256) void heads_kernel(
    const float* __restrict__ Z,
    const float* __restrict__ w_bbox, const float* __restrict__ b_bbox,
    const float* __restrict__ w_cls,  const float* __restrict__ b_cls,
    const float* __restrict__ w_reg,  const float* __restrict__ b_reg,
    const float* __restrict__ w_unc,  const float* __restrict__ b_unc,
    float* __restrict__ out, int n_rois)
{
    int idx = blockIdx.x * 256 + threadIdx.x;
    if (idx >= n_rois * 14) return;
    int n = idx / 14;
    int o = idx - n * 14;

    const float* w; float bb;
    if      (o < 8)  { w = w_bbox + o * D1;        bb = b_bbox[o]; }
    else if (o < 10) { w = w_cls  + (o - 8) * D1;  bb = b_cls[o - 8]; }
    else if (o < 12) { w = w_reg  + (o - 10) * D1; bb = b_reg[o - 10]; }
    else             { w = w_unc  + (o - 12) * D1; bb = b_unc[o - 12]; }

    const float* z = Z + (size_t)n * D1;
    float s = bb;
    for (int k = 0; k < D1; k += 4) {
        float4 zv = *(const float4*)(z + k);
        float4 wv = *(const float4*)(w + k);
        s = fmaf(zv.x, wv.x, s);
        s = fmaf(zv.y, wv.y, s);
        s = fmaf(zv.z, wv.z, s);
        s = fmaf(zv.w, wv.w, s);
    }

    int off;
    int clsOff = n_rois * 8;
    int regOff = n_rois * 8 + n_rois * 2;
    if      (o < 8)  off = n * 8 + o;
    else if (o < 10) off = clsOff + n * 2 + (o - 8);
    else if (o < 12) off = regOff + n * 4 + (o - 10) * 2;       // reg -> slot 0
    else             off = regOff + n * 4 + (o - 12) * 2 + 1;   // unc -> slot 1
    out[off] = s;
}

// ---------------------------------------------------------------------------
extern "C" void kernel_launch(void* const* d_in, const int* in_sizes, int n_in,
                              void* d_out, int out_size, void* d_ws, size_t ws_size,
                              hipStream_t stream)
{
    const float* f0   = (const float*)d_in[0];
    const float* f1   = (const float*)d_in[1];
    const float* f2   = (const float*)d_in[2];
    const float* f3   = (const float*)d_in[3];
    const float* rois = (const float*)d_in[4];
    const float* w1   = (const float*)d_in[5];
    const float* b1   = (const float*)d_in[6];
    const float* w2   = (const float*)d_in[7];
    const float* b2   = (const float*)d_in[8];
    const float* w_bbox = (const float*)d_in[9];
    const float* b_bbox = (const float*)d_in[10];
    const float* w_cls  = (const float*)d_in[11];
    const float* b_cls  = (const float*)d_in[12];
    const float* w_reg  = (const float*)d_in[13];
    const float* b_reg  = (const float*)d_in[14];
    const float* w_unc  = (const float*)d_in[15];
    const float* b_unc  = (const float*)d_in[16];
    float* out = (float*)d_out;

    int n_rois = in_sizes[4] / 5;   // 1000

    // workspace layout:
    //   pooledB bf16 [n_rois][PK]
    //   w1B     bf16 [D1][PK]
    //   w2B     bf16 [D1][D1]
    //   Y       bf16 [n_rois][D1]
    //   Z       f32  [n_rois][D1]
    ushort* pooledB = (ushort*)d_ws;
    ushort* w1B = pooledB + (size_t)n_rois * PK;
    ushort* w2B = w1B + (size_t)D1 * PK;
    ushort* Y   = w2B + (size_t)D1 * D1;
    float*  Z   = (float*)(Y + (size_t)n_rois * D1);

    // 0) weight conversions (independent of roi_align)
    {
        int n4 = (D1 * PK) / 4;
        cvt_bf16<<<(n4 + 255) / 256, 256, 0, stream>>>(w1, w1B, n4);
    }
    {
        int n4 = (D1 * D1) / 4;
        cvt_bf16<<<(n4 + 255) / 256, 256, 0, stream>>>(w2, w2B, n4);
    }
    // 1) RoIAlign -> bf16
    {
        int total = n_rois * PK;
        roi_align_kernel<<<(total + 255) / 256, 256, 0, stream>>>(
            f0, f1, f2, f3, rois, pooledB, n_rois);
    }
    // 2) FC1: [n_rois, PK] x [D1, PK]^T -> Y (bf16, relu)
    {
        dim3 grid(D1 / 64, (n_rois + 63) / 64);
        mfma_gemm_relu<1><<<grid, 256, 0, stream>>>(pooledB, w1B, b1, Y, n_rois, D1, PK);
    }
    // 3) FC2: [n_rois, D1] x [D1, D1]^T -> Z (f32, relu)
    {
        dim3 grid(D1 / 64, (n_rois + 63) / 64);
        mfma_gemm_relu<0><<<grid, 256, 0, stream>>>(Y, w2B, b2, Z, n_rois, D1, D1);
    }
    // 4) heads
    {
        int total = n_rois * 14;
        heads_kernel<<<(total + 255) / 256, 256, 0, stream>>>(
            Z, w_bbox, b_bbox, w_cls, b_cls, w_reg, b_reg, w_unc, b_unc, out, n_rois);
    }
}

// Round 4
// 286.386 us; speedup vs baseline: 2.8325x; 1.2113x over previous
//
#include <hip/hip_runtime.h>
#include <hip/hip_bf16.h>
#include <cstddef>

typedef __attribute__((ext_vector_type(8))) short short8;
typedef __attribute__((ext_vector_type(16))) float float16;

#define C_CH 192
#define PK   9408      // C_CH * 49
#define D1   768

__device__ __forceinline__ ushort f2bf(float v) {
    return __builtin_bit_cast(unsigned short, __float2bfloat16(v));
}
__device__ __forceinline__ float bf2f(ushort u) {
    return __builtin_bit_cast(float, ((unsigned int)u) << 16);
}

// ---------------------------------------------------------------------------
// fp32 -> bf16 conversion (vectorized float4 -> 4x bf16)
// ---------------------------------------------------------------------------
__global__ __launch_bounds__(256) void cvt_bf16(const float* __restrict__ in,
                                                ushort* __restrict__ out, int n4)
{
    int i = blockIdx.x * 256 + threadIdx.x;
    if (i >= n4) return;
    float4 v = ((const float4*)in)[i];
    ushort4 o;
    o.x = f2bf(v.x); o.y = f2bf(v.y); o.z = f2bf(v.z); o.w = f2bf(v.w);
    ((ushort4*)out)[i] = o;
}

// ---------------------------------------------------------------------------
// One pyramid level NCHW(fp32) -> NHWC(bf16). grid (HW/32, B), 256 thr.
// ---------------------------------------------------------------------------
__global__ __launch_bounds__(256) void repack_level(
    const float* __restrict__ in, ushort* __restrict__ out, int HW)
{
    __shared__ float sm[C_CH][33];
    int hw0 = blockIdx.x * 32;
    int b   = blockIdx.y;
    int tx = threadIdx.x & 31;
    int ty = threadIdx.x >> 5;    // 0..7

    const float* ip = in + (size_t)b * C_CH * HW + hw0;
    #pragma unroll
    for (int c = 0; c < C_CH; c += 8)
        sm[c + ty][tx] = ip[(size_t)(c + ty) * HW + tx];
    __syncthreads();

    ushort* op = out + ((size_t)b * HW + hw0) * C_CH;
    #pragma unroll
    for (int r0 = 0; r0 < 32; r0 += 8) {
        int r = r0 + ty;
        #pragma unroll
        for (int cc = 0; cc < 6; ++cc) {
            int c = cc * 32 + tx;
            op[(size_t)r * C_CH + c] = f2bf(sm[c][r]);
        }
    }
}

// ---------------------------------------------------------------------------
// RoIAlign gather from NHWC bf16: one block per RoI, 192 threads = 1/channel.
// filter >= 0: only process RoIs whose pyramid level == filter (per-level mode,
// all 4 fmap pointers then point at the same staging buffer).
// ---------------------------------------------------------------------------
__global__ __launch_bounds__(192) void roi_gather(
    const ushort* __restrict__ n0p, const ushort* __restrict__ n1p,
    const ushort* __restrict__ n2p, const ushort* __restrict__ n3p,
    const float* __restrict__ rois, ushort* __restrict__ pooled, int filter)
{
    __shared__ int   s_off[196][4];
    __shared__ float s_w[196][4];
    __shared__ ushort s_out[PK];

    const int n   = blockIdx.x;
    const int tid = threadIdx.x;

    float by1 = rois[n*5+0], bx1 = rois[n*5+1];
    float by2 = rois[n*5+2], bx2 = rois[n*5+3];
    int   b   = (int)rois[n*5+4];

    float hh = by2 - by1, ww = bx2 - bx1;
    int lvl = (int)rintf(4.0f + log2f(sqrtf(hh * ww)));
    lvl = min(max(lvl, 0), 3);
    if (filter >= 0 && lvl != filter) return;   // wave-uniform

    const ushort* fm; int H;
    if      (lvl == 0) { fm = n0p; H = 128; }
    else if (lvl == 1) { fm = n1p; H = 64;  }
    else if (lvl == 2) { fm = n2p; H = 32;  }
    else               { fm = n3p; H = 16;  }
    float Hf = (float)H;

    float y1p = by1 * Hf, x1p = bx1 * Hf;
    float y2p = by2 * Hf, x2p = bx2 * Hf;
    float bin_h = fmaxf(y2p - y1p, 1.0f) * (1.0f / 7.0f);
    float bin_w = fmaxf(x2p - x1p, 1.0f) * (1.0f / 7.0f);

    const ushort* base = fm + (size_t)b * H * H * C_CH;

    for (int s = tid; s < 196; s += 192) {      // FIX: 192 threads cover 196 entries
        int sx = s & 1, sy = (s >> 1) & 1, ij = s >> 2;
        int i = ij / 7, j = ij - i * 7;

        float gy = (float)i + 0.25f + 0.5f * (float)sy;
        float y  = y1p + gy * bin_h;
        bool  vy = (y >= -1.0f) && (y <= Hf);
        float yc = fminf(fmaxf(y, 0.0f), Hf - 1.0f);
        int   y0 = (int)floorf(yc);
        float ly = yc - (float)y0;
        int   y1i = min(y0 + 1, H - 1);

        float gx = (float)j + 0.25f + 0.5f * (float)sx;
        float x  = x1p + gx * bin_w;
        bool  vx = (x >= -1.0f) && (x <= Hf);
        float xc = fminf(fmaxf(x, 0.0f), Hf - 1.0f);
        int   x0 = (int)floorf(xc);
        float lx = xc - (float)x0;
        int   x1i = min(x0 + 1, H - 1);

        float vm = (vy && vx) ? 0.25f : 0.0f;
        s_off[s][0] = (y0  * H + x0 ) * C_CH;
        s_off[s][1] = (y0  * H + x1i) * C_CH;
        s_off[s][2] = (y1i * H + x0 ) * C_CH;
        s_off[s][3] = (y1i * H + x1i) * C_CH;
        s_w[s][0] = (1.0f - ly) * (1.0f - lx) * vm;
        s_w[s][1] = (1.0f - ly) * lx * vm;
        s_w[s][2] = ly * (1.0f - lx) * vm;
        s_w[s][3] = ly * lx * vm;
    }
    __syncthreads();

    const int c = tid;
    for (int bin = 0; bin < 49; ++bin) {
        float acc = 0.0f;
        #pragma unroll
        for (int sub = 0; sub < 4; ++sub) {
            int s = bin * 4 + sub;
            #pragma unroll
            for (int tp = 0; tp < 4; ++tp) {
                acc = fmaf(bf2f(base[s_off[s][tp] + c]), s_w[s][tp], acc);
            }
        }
        s_out[c * 49 + bin] = f2bf(acc);
    }
    __syncthreads();

    unsigned int* po = (unsigned int*)(pooled + (size_t)n * PK);
    const unsigned int* so = (const unsigned int*)s_out;
    for (int idx = tid; idx < PK / 2; idx += 192) po[idx] = so[idx];
}

// ---------------------------------------------------------------------------
// RoIAlign from NCHW fp32 (fallback path, proven): 1 thread / output element
// ---------------------------------------------------------------------------
__global__ __launch_bounds__(256) void roi_align_nchw(
    const float* __restrict__ f0, const float* __restrict__ f1,
    const float* __restrict__ f2, const float* __restrict__ f3,
    const float* __restrict__ rois, ushort* __restrict__ pooled, int n_rois)
{
    int idx = blockIdx.x * 256 + threadIdx.x;
    if (idx >= n_rois * PK) return;
    int n  = idx / PK;
    int r  = idx - n * PK;
    int c  = r / 49;
    int ij = r - c * 49;
    int i  = ij / 7;
    int j  = ij - i * 7;

    float by1 = rois[n*5+0], bx1 = rois[n*5+1];
    float by2 = rois[n*5+2], bx2 = rois[n*5+3];
    int   b   = (int)rois[n*5+4];

    float hh = by2 - by1, ww = bx2 - bx1;
    int lvl = (int)rintf(4.0f + log2f(sqrtf(hh * ww)));
    lvl = min(max(lvl, 0), 3);

    const float* fmap; int H;
    if      (lvl == 0) { fmap = f0; H = 128; }
    else if (lvl == 1) { fmap = f1; H = 64;  }
    else if (lvl == 2) { fmap = f2; H = 32;  }
    else               { fmap = f3; H = 16;  }
    float Hf = (float)H;

    float y1p = by1 * Hf, x1p = bx1 * Hf;
    float bin_h = fmaxf(by2 * Hf - y1p, 1.0f) * (1.0f / 7.0f);
    float bin_w = fmaxf(bx2 * Hf - x1p, 1.0f) * (1.0f / 7.0f);

    const float* base = fmap + ((size_t)b * C_CH + c) * (size_t)(H * H);

    float acc = 0.0f;
    #pragma unroll
    for (int sy = 0; sy < 2; ++sy) {
        float y  = y1p + ((float)i + 0.25f + 0.5f * (float)sy) * bin_h;
        bool  vy = (y >= -1.0f) && (y <= Hf);
        float yc = fminf(fmaxf(y, 0.0f), Hf - 1.0f);
        int   y0 = (int)floorf(yc);
        float ly = yc - (float)y0;
        int   y1i = min(y0 + 1, H - 1);
        #pragma unroll
        for (int sx = 0; sx < 2; ++sx) {
            float x  = x1p + ((float)j + 0.25f + 0.5f * (float)sx) * bin_w;
            bool  vx = (x >= -1.0f) && (x <= Hf);
            float xc = fminf(fmaxf(x, 0.0f), Hf - 1.0f);
            int   x0 = (int)floorf(xc);
            float lx = xc - (float)x0;
            int   x1i = min(x0 + 1, H - 1);
            if (vy && vx) {
                float v = base[y0 * H + x0 ] * (1.0f - ly) * (1.0f - lx)
                        + base[y0 * H + x1i] * (1.0f - ly) * lx
                        + base[y1i * H + x0 ] * ly * (1.0f - lx)
                        + base[y1i * H + x1i] * ly * lx;
                acc += v;
            }
        }
    }
    pooled[idx] = f2bf(acc * 0.25f);
}

// ---------------------------------------------------------------------------
// bf16 MFMA GEMM: 64x64 tile, BK=64, 4 waves of 32x32 mfma, depth-2 register
// prefetch + double-buffered LDS, XOR-swizzled conflict-free layout.
// MODE 0: fp32 out, bias+relu.  MODE 1: bf16 out, bias+relu.
// MODE 2: fp32 partial (no bias), out += blockIdx.z*M*N, k-blocks from
//         blockIdx.z*nkIters.
// ---------------------------------------------------------------------------
template<int MODE>
__global__ __launch_bounds__(256) void mfma_gemm(
    const ushort* __restrict__ A,   // [M][K] bf16
    const ushort* __restrict__ W,   // [N][K] bf16
    const float*  __restrict__ bias,
    void* __restrict__ outp,
    int M, int N, int K, int nkIters)
{
    __shared__ char ldsA[2][8192];
    __shared__ char ldsB[2][8192];

    const int t    = threadIdx.x;
    const int lane = t & 63;
    const int wave = t >> 6;
    const int wm = wave >> 1, wn = wave & 1;

    const int m0 = blockIdx.y * 64;
    const int n0 = blockIdx.x * 64;
    const int kb = (MODE == 2) ? blockIdx.z * nkIters : 0;

    const int ks   = t & 3;
    const int mrow = t >> 2;
    const int g    = mrow >> 5;
    const int rw   = mrow & 31;
    const int lof0 = ks*2048 + g*1024 + ((     rw) ^ (ks<<2))*16;
    const int lof1 = ks*2048 + g*1024 + ((32 + rw) ^ (ks<<2))*16;

    const int arow = min(m0 + mrow, M-1);
    const int brow = n0 + mrow;
    const ushort* ap = A + (size_t)arow * K + (size_t)kb * 64 + ks*16;
    const ushort* bp = W + (size_t)brow * K + (size_t)kb * 64 + ks*16;

    const int nk = nkIters;

    float4 ra0, ra1, rb0, rb1;
    float4 qa0, qa1, qb0, qb1;

    ra0 = ((const float4*)ap)[0]; ra1 = ((const float4*)ap)[1];
    rb0 = ((const float4*)bp)[0]; rb1 = ((const float4*)bp)[1];
    *(float4*)&ldsA[0][lof0] = ra0; *(float4*)&ldsA[0][lof1] = ra1;
    *(float4*)&ldsB[0][lof0] = rb0; *(float4*)&ldsB[0][lof1] = rb1;
    {
        int k1 = min(1, nk - 1);
        const ushort* ap1 = ap + (size_t)k1 * 64;
        const ushort* bp1 = bp + (size_t)k1 * 64;
        ra0 = ((const float4*)ap1)[0]; ra1 = ((const float4*)ap1)[1];
        rb0 = ((const float4*)bp1)[0]; rb1 = ((const float4*)bp1)[1];
    }
    __syncthreads();

    float16 acc = {};

    for (int kt = 0; kt < nk; ++kt) {
        {
            int k2 = min(kt + 2, nk - 1);
            const ushort* ap2 = ap + (size_t)k2 * 64;
            const ushort* bp2 = bp + (size_t)k2 * 64;
            qa0 = ((const float4*)ap2)[0]; qa1 = ((const float4*)ap2)[1];
            qb0 = ((const float4*)bp2)[0]; qb1 = ((const float4*)bp2)[1];
        }
        if (kt + 1 < nk) {
            char* dA = ldsA[(kt+1)&1]; char* dB = ldsB[(kt+1)&1];
            *(float4*)&dA[lof0] = ra0; *(float4*)&dA[lof1] = ra1;
            *(float4*)&dB[lof0] = rb0; *(float4*)&dB[lof1] = rb1;
        }
        const char* sA = ldsA[kt&1]; const char* sB = ldsB[kt&1];
        #pragma unroll
        for (int s = 0; s < 4; ++s) {
            int ro = s*2048 + (lane ^ (s<<2))*16;
            short8 af = *(const short8*)&sA[wm*1024 + ro];
            short8 bf = *(const short8*)&sB[wn*1024 + ro];
            acc = __builtin_amdgcn_mfma_f32_32x32x16_bf16(af, bf, acc, 0, 0, 0);
        }
        __syncthreads();
        ra0 = qa0; ra1 = qa1; rb0 = qb0; rb1 = qb1;
    }

    const int col   = lane & 31;
    const int rbase = 4 * (lane >> 5);
    const int nG    = n0 + wn*32 + col;

    if (MODE == 2) {
        float* O = (float*)outp + (size_t)blockIdx.z * M * N;
        #pragma unroll
        for (int r = 0; r < 16; ++r) {
            int row = (r & 3) + 8*(r >> 2) + rbase;
            int mG  = m0 + wm*32 + row;
            if (mG < M) O[(size_t)mG * N + nG] = acc[r];
        }
    } else if (MODE == 1) {
        const float bv = bias[nG];
        ushort* O = (ushort*)outp;
        #pragma unroll
        for (int r = 0; r < 16; ++r) {
            int row = (r & 3) + 8*(r >> 2) + rbase;
            int mG  = m0 + wm*32 + row;
            if (mG < M) O[(size_t)mG * N + nG] = f2bf(fmaxf(acc[r] + bv, 0.0f));
        }
    } else {
        const float bv = bias[nG];
        float* O = (float*)outp;
        #pragma unroll
        for (int r = 0; r < 16; ++r) {
            int row = (r & 3) + 8*(r >> 2) + rbase;
            int mG  = m0 + wm*32 + row;
            if (mG < M) O[(size_t)mG * N + nG] = fmaxf(acc[r] + bv, 0.0f);
        }
    }
}

// ---------------------------------------------------------------------------
// Split-K reduce: Y[m][n] = bf16(relu(bias[n] + sum_s P[s][m][n]))
// ---------------------------------------------------------------------------
__global__ __launch_bounds__(256) void reduce_relu_bf16(
    const float* __restrict__ P, const float* __restrict__ bias,
    ushort* __restrict__ Y, int MN, int N, int S)
{
    int idx = blockIdx.x * 256 + threadIdx.x;
    if (idx >= MN / 4) return;
    float4 s = ((const float4*)P)[idx];
    for (int k = 1; k < S; ++k) {
        float4 p = ((const float4*)(P + (size_t)k * MN))[idx];
        s.x += p.x; s.y += p.y; s.z += p.z; s.w += p.w;
    }
    int n4 = idx % (N / 4);
    float4 bv = ((const float4*)bias)[n4];
    ushort4 o;
    o.x = f2bf(fmaxf(s.x + bv.x, 0.0f));
    o.y = f2bf(fmaxf(s.y + bv.y, 0.0f));
    o.z = f2bf(fmaxf(s.z + bv.z, 0.0f));
    o.w = f2bf(fmaxf(s.w + bv.w, 0.0f));
    ((ushort4*)Y)[idx] = o;
}

// ---------------------------------------------------------------------------
// Heads: 14 outputs per RoI, K=768 fp32 dot each
// ---------------------------------------------------------------------------
__global__ __launch_bounds__(256) void heads_kernel(
    const float* __restrict__ Z,
    const float* __restrict__ w_bbox, const float* __restrict__ b_bbox,
    const float* __restrict__ w_cls,  const float* __restrict__ b_cls,
    const float* __restrict__ w_reg,  const float* __restrict__ b_reg,
    const float* __restrict__ w_unc,  const float* __restrict__ b_unc,
    float* __restrict__ out, int n_rois)
{
    int idx = blockIdx.x * 256 + threadIdx.x;
    if (idx >= n_rois * 14) return;
    int n = idx / 14;
    int o = idx - n * 14;

    const float* w; float bb;
    if      (o < 8)  { w = w_bbox + o * D1;        bb = b_bbox[o]; }
    else if (o < 10) { w = w_cls  + (o - 8) * D1;  bb = b_cls[o - 8]; }
    else if (o < 12) { w = w_reg  + (o - 10) * D1; bb = b_reg[o - 10]; }
    else             { w = w_unc  + (o - 12) * D1; bb = b_unc[o - 12]; }

    const float* z = Z + (size_t)n * D1;
    float s = bb;
    for (int k = 0; k < D1; k += 4) {
        float4 zv = *(const float4*)(z + k);
        float4 wv = *(const float4*)(w + k);
        s = fmaf(zv.x, wv.x, s);
        s = fmaf(zv.y, wv.y, s);
        s = fmaf(zv.z, wv.z, s);
        s = fmaf(zv.w, wv.w, s);
    }

    int off;
    int clsOff = n_rois * 8;
    int regOff = n_rois * 8 + n_rois * 2;
    if      (o < 8)  off = n * 8 + o;
    else if (o < 10) off = clsOff + n * 2 + (o - 8);
    else if (o < 12) off = regOff + n * 4 + (o - 10) * 2;
    else             off = regOff + n * 4 + (o - 12) * 2 + 1;
    out[off] = s;
}

// ---------------------------------------------------------------------------
extern "C" void kernel_launch(void* const* d_in, const int* in_sizes, int n_in,
                              void* d_out, int out_size, void* d_ws, size_t ws_size,
                              hipStream_t stream)
{
    const float* f0   = (const float*)d_in[0];
    const float* f1   = (const float*)d_in[1];
    const float* f2   = (const float*)d_in[2];
    const float* f3   = (const float*)d_in[3];
    const float* rois = (const float*)d_in[4];
    const float* w1   = (const float*)d_in[5];
    const float* b1   = (const float*)d_in[6];
    const float* w2   = (const float*)d_in[7];
    const float* b2   = (const float*)d_in[8];
    const float* w_bbox = (const float*)d_in[9];
    const float* b_bbox = (const float*)d_in[10];
    const float* w_cls  = (const float*)d_in[11];
    const float* b_cls  = (const float*)d_in[12];
    const float* w_reg  = (const float*)d_in[13];
    const float* b_reg  = (const float*)d_in[14];
    const float* w_unc  = (const float*)d_in[15];
    const float* b_unc  = (const float*)d_in[16];
    float* out = (float*)d_out;

    const int n_rois = in_sizes[4] / 5;                 // 1000
    const int B      = in_sizes[0] / (C_CH * 128 * 128); // 4

    // sizes in bytes
    const size_t nh0B = (size_t)B * 16384 * C_CH * 2;   // 25,165,824 (B=4)
    const size_t nh1B = (size_t)B * 4096  * C_CH * 2;
    const size_t nh2B = (size_t)B * 1024  * C_CH * 2;
    const size_t nh3B = (size_t)B * 256   * C_CH * 2;
    const size_t nhAll = nh0B + nh1B + nh2B + nh3B;     // 33,423,360
    const size_t poolB = (size_t)n_rois * PK * 2;       // 18,816,000
    const size_t w1Bb  = (size_t)D1 * PK * 2;           // 14,450,688
    const size_t w2Bb  = (size_t)D1 * D1 * 2;
    const size_t Yb    = (size_t)n_rois * D1 * 2;
    const size_t Zb    = (size_t)n_rois * D1 * 4;
    const int    SPLIT = 3;                             // 147 = 3 * 49
    const size_t Pb    = (size_t)SPLIT * n_rois * D1 * 4;
    const size_t smallB = w2Bb + Yb + Zb;

    const size_t needX = nhAll + poolB + smallB;        // ~58.0 MB
    const size_t needY = nh0B  + poolB + smallB;        // ~49.8 MB
    // both plans alias w1B+P into the (dead) nhwc region: w1Bb + Pb <= nh0B

    char* ws = (char*)d_ws;

    if (ws_size >= needX || ws_size >= needY) {
        const bool allRes = (ws_size >= needX);
        const size_t r1sz = allRes ? nhAll : nh0B;

        ushort* nh0 = (ushort*)ws;
        ushort* nh1 = allRes ? nh0 + nh0B/2 : nh0;
        ushort* nh2 = allRes ? nh1 + nh1B/2 : nh0;
        ushort* nh3 = allRes ? nh2 + nh2B/2 : nh0;
        ushort* w1B = (ushort*)ws;                       // alias, used after gather
        float*  P   = (float*)(ws + w1Bb);               // alias, after gather
        ushort* pooledB = (ushort*)(ws + r1sz);
        ushort* w2B = (ushort*)(ws + r1sz + poolB);
        ushort* Y   = w2B + w2Bb/2;
        float*  Z   = (float*)((char*)Y + Yb);

        if (allRes) {
            repack_level<<<dim3(16384/32, B), 256, 0, stream>>>(f0, nh0, 16384);
            repack_level<<<dim3(4096/32,  B), 256, 0, stream>>>(f1, nh1, 4096);
            repack_level<<<dim3(1024/32,  B), 256, 0, stream>>>(f2, nh2, 1024);
            repack_level<<<dim3(256/32,   B), 256, 0, stream>>>(f3, nh3, 256);
            roi_gather<<<n_rois, 192, 0, stream>>>(nh0, nh1, nh2, nh3, rois, pooledB, -1);
        } else {
            repack_level<<<dim3(16384/32, B), 256, 0, stream>>>(f0, nh0, 16384);
            roi_gather<<<n_rois, 192, 0, stream>>>(nh0, nh0, nh0, nh0, rois, pooledB, 0);
            repack_level<<<dim3(4096/32,  B), 256, 0, stream>>>(f1, nh0, 4096);
            roi_gather<<<n_rois, 192, 0, stream>>>(nh0, nh0, nh0, nh0, rois, pooledB, 1);
            repack_level<<<dim3(1024/32,  B), 256, 0, stream>>>(f2, nh0, 1024);
            roi_gather<<<n_rois, 192, 0, stream>>>(nh0, nh0, nh0, nh0, rois, pooledB, 2);
            repack_level<<<dim3(256/32,   B), 256, 0, stream>>>(f3, nh0, 256);
            roi_gather<<<n_rois, 192, 0, stream>>>(nh0, nh0, nh0, nh0, rois, pooledB, 3);
        }
        // weight conversions (w1B aliases nhwc region -> must follow gather; stream-ordered)
        cvt_bf16<<<((D1*PK/4) + 255)/256, 256, 0, stream>>>(w1, w1B, D1*PK/4);
        cvt_bf16<<<((D1*D1/4) + 255)/256, 256, 0, stream>>>(w2, w2B, D1*D1/4);
        // FC1 split-K + reduce
        {
            dim3 grid(D1/64, (n_rois + 63)/64, SPLIT);
            mfma_gemm<2><<<grid, 256, 0, stream>>>(pooledB, w1B, nullptr, P,
                                                   n_rois, D1, PK, (PK/64)/SPLIT);
            int MN = n_rois * D1;
            reduce_relu_bf16<<<(MN/4 + 255)/256, 256, 0, stream>>>(P, b1, Y, MN, D1, SPLIT);
        }
        // FC2 -> Z fp32
        {
            dim3 grid(D1/64, (n_rois + 63)/64, 1);
            mfma_gemm<0><<<grid, 256, 0, stream>>>(Y, w2B, b2, Z, n_rois, D1, D1, D1/64);
        }
        heads_kernel<<<(n_rois*14 + 255)/256, 256, 0, stream>>>(
            Z, w_bbox, b_bbox, w_cls, b_cls, w_reg, b_reg, w_unc, b_unc, out, n_rois);
    } else {
        // ------- fallback: proven 39.1 MB layout (round-2 path) -------
        ushort* pooledB = (ushort*)ws;
        ushort* w1B = pooledB + poolB/2;
        ushort* w2B = w1B + w1Bb/2;
        ushort* Y   = w2B + w2Bb/2;
        float*  Z   = (float*)((char*)Y + Yb);

        cvt_bf16<<<((D1*PK/4) + 255)/256, 256, 0, stream>>>(w1, w1B, D1*PK/4);
        cvt_bf16<<<((D1*D1/4) + 255)/256, 256, 0, stream>>>(w2, w2B, D1*D1/4);
        {
            int total = n_rois * PK;
            roi_align_nchw<<<(total + 255)/256, 256, 0, stream>>>(
                f0, f1, f2, f3, rois, pooledB, n_rois);
        }
        {
            dim3 grid(D1/64, (n_rois + 63)/64);
            mfma_gemm<1><<<grid, 256, 0, stream>>>(pooledB, w1B, b1, Y, n_rois, D1, PK, PK/64);
        }
        {
            dim3 grid(D1/64, (n_rois + 63)/64);
            mfma_gemm<0><<<grid, 256, 0, stream>>>(Y, w2B, b2, Z, n_rois, D1, D1, D1/64);
        }
        heads_kernel<<<(n_rois*14 + 255)/256, 256, 0, stream>>>(
            Z, w_bbox, b_bbox, w_cls, b_cls, w_reg, b_reg, w_unc, b_unc, out, n_rois);
    }
}